// Round 6
// baseline (641.517 us; speedup 1.0000x reference)
//
#include <hip/hip_runtime.h>
#include <hip/hip_bf16.h>
#include <math.h>

// Problem constants (from reference)
constexpr int Bb   = 32;
constexpr int Ls   = 110;
constexpr int Gs   = 512;
constexpr int Ns   = 40;
constexpr int Ds   = 300;
constexpr int WPc  = 10;
constexpr int WFc  = 10;
constexpr int MAXNc = 110;
constexpr float EPSf  = 1e-8f;
constexpr float CLIPf = 1.0f - 1e-6f;
constexpr int BL = Bb * Ls;        // 3520
constexpr int BPITCH = 328;        // LDS row pitch in shorts (t/d range 0..319)

typedef __attribute__((ext_vector_type(8))) short short8_t;
typedef __attribute__((ext_vector_type(4))) float floatx4;

__device__ __forceinline__ unsigned short bf16r(float f) {
  unsigned u = __float_as_uint(f);
  u += 0x7fffu + ((u >> 16) & 1u);          // RNE to bf16
  return (unsigned short)(u >> 16);
}

__device__ __forceinline__ unsigned pkbf(float lo, float hi) {
  unsigned a = __float_as_uint(lo), b = __float_as_uint(hi);
  a += 0x7fffu + ((a >> 16) & 1u);
  b += 0x7fffu + ((b >> 16) & 1u);
  return (a >> 16) | (b & 0xffff0000u);
}

__device__ __forceinline__ short8_t cvt8(const float4 v0, const float4 v1) {
  union { short8_t s; unsigned u[4]; } p;
  p.u[0] = pkbf(v0.x, v0.y);
  p.u[1] = pkbf(v0.z, v0.w);
  p.u[2] = pkbf(v1.x, v1.y);
  p.u[3] = pkbf(v1.z, v1.w);
  return p.s;
}

// ---------------------------------------------------------------------------
// Kernel 0: transpose W_sem (512x512) so the sem GEMM reads it coalesced.
// ---------------------------------------------------------------------------
__global__ __launch_bounds__(256) void transpose_wsem(const float* __restrict__ w,
                                                      float* __restrict__ wt) {
  __shared__ float tile[32][33];
  const int bx = blockIdx.x * 32;
  const int by = blockIdx.y * 32;
  const int tx = threadIdx.x;   // 0..31
  const int ty = threadIdx.y;   // 0..7
#pragma unroll
  for (int r = ty; r < 32; r += 8)
    tile[r][tx] = w[(by + r) * Gs + (bx + tx)];
  __syncthreads();
#pragma unroll
  for (int r = ty; r < 32; r += 8)
    wt[(bx + r) * Gs + (by + tx)] = tile[tx][r];   // wt[t][s] = w[s][t]
}

// ---------------------------------------------------------------------------
// Kernel 0b: Wc -> MFMA-fragment-major bf16 table.
// wctf[((nb*10 + c)*64 + lane)*8 + e] = bf16(Wc[s][t]), zero-padded,
//   s = c*32 + (lane>>4)*8 + e,  t = nb*16 + (lane&15).
// Serves BOTH as B-frag (Y = K.Wc) and, by the operand-swap identity
// (A-frag row=l16/k=quad*8+e == B-frag k=quad*8+e/col=l16 per-lane data),
// as A-frag for Y^T = Wc^T . K^T -- which is how con_fused uses it.
// ---------------------------------------------------------------------------
__global__ __launch_bounds__(64) void wctf_prep(const float* __restrict__ wc,
                                                short* __restrict__ wctf) {
  const int fid = blockIdx.x;       // nb*10 + c, 200 total
  const int nb = fid / 10, c = fid % 10;
  const int lane = threadIdx.x;
  const int t = nb * 16 + (lane & 15);
  const int s0 = c * 32 + (lane >> 4) * 8;
  short8_t v;
#pragma unroll
  for (int e = 0; e < 8; ++e) {
    const int s = s0 + e;
    const float f = (s < Ds && t < Ds) ? wc[s * Ds + t] : 0.f;
    v[e] = (short)bf16r(f);
  }
  *reinterpret_cast<short8_t*>(wctf + ((size_t)fid * 64 + lane) * 8) = v;
}

// ---------------------------------------------------------------------------
// Kernel 1: att_sem[bl,s] = sum_t W[s,t] * x[bl,t]
// ---------------------------------------------------------------------------
__global__ __launch_bounds__(512) void sem_gemm(const float* __restrict__ nf,
                                                const float* __restrict__ wt,
                                                float* __restrict__ att_sem,
                                                float* __restrict__ na_arr) {
  const int bl0 = blockIdx.x * 8;
  const int s = threadIdx.x;
  const float* __restrict__ x0 = nf + (size_t)bl0 * Gs;
  float acc[8];
#pragma unroll
  for (int r = 0; r < 8; ++r) acc[r] = 0.f;
#pragma unroll 4
  for (int t = 0; t < Gs; ++t) {
    const float wv = wt[t * Gs + s];
#pragma unroll
    for (int r = 0; r < 8; ++r) acc[r] = fmaf(wv, x0[r * Gs + t], acc[r]);
  }
#pragma unroll
  for (int r = 0; r < 8; ++r) att_sem[(size_t)(bl0 + r) * Gs + s] = acc[r];

  __shared__ float partial[8][8];
  const int wave = s >> 6, lane = s & 63;
#pragma unroll
  for (int r = 0; r < 8; ++r) {
    float v = acc[r] * acc[r];
#pragma unroll
    for (int off = 32; off > 0; off >>= 1) v += __shfl_xor(v, off);
    if (lane == 0) partial[r][wave] = v;
  }
  __syncthreads();
  if (s < 8) {
    float sum = 0.f;
#pragma unroll
    for (int w2 = 0; w2 < 8; ++w2) sum += partial[s][w2];
    na_arr[bl0 + s] = fmaxf(sqrtf(sum), EPSf);
  }
}

// ---------------------------------------------------------------------------
// Kernel 2: banded semantic attention + softmax. One block per (b,j).
// Writes the FULL output row (zeros outside window) -> serves as out init.
// ---------------------------------------------------------------------------
__global__ __launch_bounds__(256) void sem_attn(const float* __restrict__ nf,
                                                const float* __restrict__ att_sem,
                                                const float* __restrict__ na_arr,
                                                const int* __restrict__ tlen,
                                                float* __restrict__ out) {
  const int blk = blockIdx.x;
  const int b = blk / Ls, j = blk % Ls;
  const int len = tlen[b];
  float* __restrict__ orow = out + (size_t)(b * Ls + j) * MAXNc;
  if (j >= len) {
    for (int k = threadIdx.x; k < MAXNc; k += 256) orow[k] = 0.f;
    return;
  }
  const int k0 = max(j - WPc, 0);
  const int k1 = min(j + WFc, len - 1);
  const int nk = k1 - k0 + 1;   // <= 21

  __shared__ float xs[Gs];
  __shared__ float sc[21];
  __shared__ float red[4];

  const float* __restrict__ x = nf + (size_t)(b * Ls + j) * Gs;
  float ss = 0.f;
  for (int t = threadIdx.x; t < Gs; t += 256) {
    const float v = x[t];
    xs[t] = v;
    ss += v * v;
  }
  const int wave = threadIdx.x >> 6, lane = threadIdx.x & 63;
#pragma unroll
  for (int off = 32; off > 0; off >>= 1) ss += __shfl_xor(ss, off);
  if (lane == 0) red[wave] = ss;
  __syncthreads();
  const float nfn = fmaxf(sqrtf(red[0] + red[1] + red[2] + red[3]), EPSf);

  for (int i = wave; i < nk; i += 4) {
    const int k = k0 + i;
    const float* __restrict__ as = att_sem + (size_t)(b * Ls + k) * Gs;
    float d = 0.f;
#pragma unroll
    for (int t = lane; t < Gs; t += 64) d = fmaf(xs[t], as[t], d);
#pragma unroll
    for (int off = 32; off > 0; off >>= 1) d += __shfl_xor(d, off);
    if (lane == 0) {
      float cs = d / (nfn * na_arr[b * Ls + k]);
      cs = fminf(fmaxf(cs, -CLIPf), CLIPf);
      sc[i] = 1.0f - acosf(cs) * (float)(1.0 / M_PI);
    }
  }
  __syncthreads();
  if (threadIdx.x == 0) {
    float m = -1e30f;
    for (int i = 0; i < nk; ++i) m = fmaxf(m, sc[i]);
    red[0] = m;
  }
  __syncthreads();
  const float m = red[0];
  if ((int)threadIdx.x < nk) sc[threadIdx.x] = expf(sc[threadIdx.x] - m);
  __syncthreads();
  if (threadIdx.x == 0) {
    float s = 0.f;
    for (int i = 0; i < nk; ++i) s += sc[i];
    red[1] = 1.0f / fmaxf(s, EPSf);
  }
  __syncthreads();
  const float inv = red[1];
  for (int k = threadIdx.x; k < MAXNc; k += 256) {
    float v = 0.f;
    if (k >= k0 && k <= k1) v = 0.5f * sc[k - k0] * inv;
    orow[k] = v;
  }
}

// ---------------------------------------------------------------------------
// Kernel 3 (round-12): FULLY FUSED contextual path. One block per (b, k-tile).
// Reads kn exactly once from HBM; Y never touches HBM.
// Per n (pipelined, 1 barrier/n):
//   stage:  all 640 lanes cooperatively load kn[k-tile, n+1] fp32 -> bf16
//           klds (double-buffered).
//   phase2: wave w computes Y^T tiles T={w, w+10}: mfma(A = WcT frags held
//           in 80 VGPRs for the whole kernel, B = klds chunk) -> ylds[n&1],
//           f32-exact row-ssq -> rowss[n][k] (LDS atomic, per-n slot).
//   phase3 (waves 0..2, for n-1): banded Gram S = mfma(kn_j fp32->bf16,
//           Y^T from ylds), f32-exact ||kn_j||, w = aff/max(aff*sqrt(rowss)),
//           outacc += kinv * w * |S|   (identical numerics to r5 con_attn).
// Output: unique (j,k) owner -> plain += onto sem_attn's initialized rows.
// XCD swizzle: 7 k-tiles x 4 b colocate -> per-n working set ~1.5MB/XCD L2.
// ---------------------------------------------------------------------------
__global__ __launch_bounds__(640, 3) void con_fused(const float* __restrict__ kn,
                                                    const short* __restrict__ wctf,
                                                    const float* __restrict__ anew,
                                                    const int* __restrict__ tlen,
                                                    float* __restrict__ out) {
  const int lin = blockIdx.x;          // 224 = 8 xcd * 28 slots
  const int xcd = lin & 7, slot = lin >> 3;
  const int b = xcd * 4 + slot / 7;
  const int kt = slot % 7;
  const int k0 = kt * 16;
  const int len = tlen[b];
  if (k0 >= len) return;               // whole k-tile dead; before any barrier
  const int jbase = min(max(k0 - WPc, 0), Ls - 48);   // covers band of k-tile

  const int tid = threadIdx.x;
  const int wave = tid >> 6, lane = tid & 63;
  const int quad = lane >> 4, l16 = lane & 15;

  __shared__ short klds[2][16 * BPITCH];   // kn[k-tile, n] bf16, dbuf (21 KB)
  __shared__ short ylds[2][16 * BPITCH];   // Y^T[k][t] bf16, dbuf (21 KB)
  __shared__ float rowss[40][16];          // per-n ||Y_k||^2 slots (2.5 KB)

  reinterpret_cast<float*>(rowss)[tid] = 0.f;   // 640 == 40*16 exactly

  // Wc^T fragment hold: wave w owns t-tiles {w, w+10}; 20 frags = 80 VGPR.
  short8_t Awc[2][10];
#pragma unroll
  for (int tt = 0; tt < 2; ++tt)
#pragma unroll
    for (int c = 0; c < 10; ++c)
      Awc[tt][c] = *reinterpret_cast<const short8_t*>(
          wctf + ((size_t)((wave + 10 * tt) * 10 + c) * 64 + lane) * 8);

  // cooperative stage: lane -> (row = tid/40, 8-elem group = tid%40)
  const int srow = tid / 40, scol = tid % 40;
  const float* __restrict__ ksrc =
      kn + ((size_t)(b * Ls + min(k0 + srow, Ls - 1)) * Ns) * Ds + scol * 8;

  auto STAGE = [&](int np) {
    float4 v0 = make_float4(0.f, 0.f, 0.f, 0.f);
    float4 v1 = make_float4(0.f, 0.f, 0.f, 0.f);
    const float* src = ksrc + (size_t)np * Ds;
    if (scol < 37) {                    // elems scol*8 .. +7 all < 300
      v0 = *reinterpret_cast<const float4*>(src);
      v1 = *reinterpret_cast<const float4*>(src + 4);
    } else if (scol == 37) {            // 296..299 valid
      v0 = *reinterpret_cast<const float4*>(src);
    }
    *reinterpret_cast<short8_t*>(&klds[np & 1][srow * BPITCH + scol * 8]) =
        cvt8(v0, v1);
  };

  float outacc[4] = {0.f, 0.f, 0.f, 0.f};
  const int jrow = jbase + wave * 16 + l16;            // waves 0..2 only use
  const float* __restrict__ ajbase =
      kn + ((size_t)(b * Ls + jrow) * Ns) * Ds + quad * 8;
  const int mmk = (b * Ls + min(k0 + l16, Ls - 1)) * Ns;

  auto PHASE3 = [&](int n) {
    const int buf = n & 1;
    const float* aj = ajbase + (size_t)n * Ds;
    floatx4 S = (floatx4){0.f, 0.f, 0.f, 0.f};
    float ssq = 0.f;
#pragma unroll
    for (int c = 0; c < 10; ++c) {
      float4 v0 = make_float4(0.f, 0.f, 0.f, 0.f);
      float4 v1 = make_float4(0.f, 0.f, 0.f, 0.f);
      if (c < 9) {
        v0 = *reinterpret_cast<const float4*>(aj + c * 32);
        v1 = *reinterpret_cast<const float4*>(aj + c * 32 + 4);
      } else {
        if (quad == 0) {                 // 288..295
          v0 = *reinterpret_cast<const float4*>(aj + 288);
          v1 = *reinterpret_cast<const float4*>(aj + 292);
        } else if (quad == 1) {          // 296..299 (aj has +quad*8)
          v0 = *reinterpret_cast<const float4*>(aj + 288);
        }
      }
      ssq += v0.x * v0.x + v0.y * v0.y + v0.z * v0.z + v0.w * v0.w +
             v1.x * v1.x + v1.y * v1.y + v1.z * v1.z + v1.w * v1.w;
      const short8_t afrag = cvt8(v0, v1);
      const short8_t bfrag = *reinterpret_cast<const short8_t*>(
          &ylds[buf][l16 * BPITCH + c * 32 + quad * 8]);
      S = __builtin_amdgcn_mfma_f32_16x16x32_bf16(afrag, bfrag, S, 0, 0, 0);
    }
    ssq += __shfl_xor(ssq, 16);
    ssq += __shfl_xor(ssq, 32);
    const float kinv = 1.0f / fmaxf(sqrtf(ssq), EPSf);
    // weight for k = k0 + l16 at this n
    const float a = anew[mmk + n];
    const float aff = (sqrtf((a - 0.5f) * (a - 0.5f) + 0.25f * a * a) - 0.06467f) *
                      (1.0f / 0.607468f);
    const float w = aff / fmaxf(aff * sqrtf(rowss[n][l16]), EPSf);
#pragma unroll
    for (int r = 0; r < 4; ++r) {
      const float kv = __shfl(kinv, quad * 4 + r);
      outacc[r] = fmaf(kv * w, fabsf(S[r]), outacc[r]);
    }
  };

  STAGE(0);
  __syncthreads();

  for (int n = 0; n < 40; ++n) {
    if (n < 39) STAGE(n + 1);
    // phase2: Y^T for this wave's two t-tiles
    {
      const int buf = n & 1;
      floatx4 a0 = (floatx4){0.f, 0.f, 0.f, 0.f};
      floatx4 a1 = (floatx4){0.f, 0.f, 0.f, 0.f};
#pragma unroll
      for (int c = 0; c < 10; ++c) {
        const short8_t bfrag = *reinterpret_cast<const short8_t*>(
            &klds[buf][l16 * BPITCH + c * 32 + quad * 8]);
        a0 = __builtin_amdgcn_mfma_f32_16x16x32_bf16(Awc[0][c], bfrag, a0, 0, 0, 0);
        a1 = __builtin_amdgcn_mfma_f32_16x16x32_bf16(Awc[1][c], bfrag, a1, 0, 0, 0);
      }
      float ss = 0.f;
#pragma unroll
      for (int r = 0; r < 4; ++r) {
        ss += a0[r] * a0[r] + a1[r] * a1[r];
        ylds[buf][l16 * BPITCH + wave * 16 + quad * 4 + r] = (short)bf16r(a0[r]);
        ylds[buf][l16 * BPITCH + (wave + 10) * 16 + quad * 4 + r] =
            (short)bf16r(a1[r]);
      }
      ss += __shfl_xor(ss, 16);
      ss += __shfl_xor(ss, 32);
      if (quad == 0) atomicAdd(&rowss[n][l16], ss);
    }
    if (wave < 3 && n >= 1) PHASE3(n - 1);
    __syncthreads();
  }

  if (wave < 3) {
    PHASE3(39);
#pragma unroll
    for (int r = 0; r < 4; ++r) {
      const int j = jbase + wave * 16 + quad * 4 + r;
      const int k = k0 + l16;
      if (j < len && k < len && k >= j - WPc && k <= j + WFc)
        out[(size_t)(b * Ls + j) * MAXNc + k] += 5.0f * outacc[r];  // 0.5 * 10
    }
  }
}

// ---------------------------------------------------------------------------
extern "C" void kernel_launch(void* const* d_in, const int* in_sizes, int n_in,
                              void* d_out, int out_size, void* d_ws, size_t ws_size,
                              hipStream_t stream) {
  const float* nf   = (const float*)d_in[0];   // (B,L,G)
  const float* kn   = (const float*)d_in[1];   // (B,L,N,D)
  const float* anew = (const float*)d_in[2];   // (B,L,N)
  const float* wsem = (const float*)d_in[3];   // (G,G)
  const float* wcon = (const float*)d_in[4];   // (D,D)
  const int*   tlen = (const int*)d_in[5];     // (B,)
  float* out = (float*)d_out;

  // workspace layout (~8.5 MB)
  float* att_sem = (float*)d_ws;                            // 3520*512 f32
  float* na_arr  = att_sem + (size_t)BL * Gs;               // 3520 f32
  float* wt      = na_arr + BL;                             // 512*512 f32
  short* wctf    = (short*)(wt + (size_t)Gs * Gs);          // 200*64*8 bf16 (200 KB)

  transpose_wsem<<<dim3(16, 16), dim3(32, 8), 0, stream>>>(wsem, wt);
  wctf_prep<<<200, 64, 0, stream>>>(wcon, wctf);
  sem_gemm<<<BL / 8, 512, 0, stream>>>(nf, wt, att_sem, na_arr);
  sem_attn<<<BL, 256, 0, stream>>>(nf, att_sem, na_arr, tlen, out);
  con_fused<<<224, 640, 0, stream>>>(kn, wctf, anew, tlen, out);
}